// Round 5
// baseline (275.381 us; speedup 1.0000x reference)
//
#include <hip/hip_runtime.h>
#include <math.h>

#define NMOL  1024
#define N     128          // atoms per molecule (Schur-reduced SPD system size)
#define NELEM 10
#define BLOCK 256
#define PW    8            // panel width
#define NPAN  16           // 128 / 8
#define PSTR  12           // panel-column buffer row stride (floats, 48B = 16B-mult)
#define USTR  132          // U-panel row stride (cols 0..129 used: 128=rhsY, 129=rhsZ)

typedef __attribute__((ext_vector_type(4))) float f4;

// thread t: h = t>>7 (0: cols 0..63 = chunks 0..15; 1: cols 64..127 = chunks 16..31)
//           r = t&127 (row). Register file Ar[16] holds the half-row.

__device__ __forceinline__ void get2(const f4* Ar, int q, f4& a0, f4& a1) {
    switch (q) {
        case 0: a0 = Ar[0];  a1 = Ar[1];  break;
        case 1: a0 = Ar[2];  a1 = Ar[3];  break;
        case 2: a0 = Ar[4];  a1 = Ar[5];  break;
        case 3: a0 = Ar[6];  a1 = Ar[7];  break;
        case 4: a0 = Ar[8];  a1 = Ar[9];  break;
        case 5: a0 = Ar[10]; a1 = Ar[11]; break;
        case 6: a0 = Ar[12]; a1 = Ar[13]; break;
        default: a0 = Ar[14]; a1 = Ar[15]; break;
    }
}

__global__ __launch_bounds__(BLOCK, 3) void ceq_solve_kernel(
    const float* __restrict__ eneg,
    const float* __restrict__ positions,
    const float* __restrict__ node_attrs,
    const float* __restrict__ hardness,
    const float* __restrict__ total_charge,
    const int*   __restrict__ atomic_numbers,
    float* __restrict__ out)
{
    __shared__ __align__(16) float P[N * PSTR];        // staged panel columns (128 x 8)
    __shared__ __align__(16) float Up[PW * USTR];      // staged panel rows (8 x 130)
    __shared__ __align__(16) float Ublk[NPAN][PW][PW]; // per-panel 8x8 diag blocks (L11\U11)
    __shared__ float rhsY[N], rhsZ[N];                 // forward-substituted RHS
    __shared__ float sxY[N], sxZ[N];                   // back-sub solutions
    __shared__ float px[N], py[N], pz[N], sg[N], dgv[N];
    __shared__ float lamS;

    const int m    = blockIdx.x;
    const int tid  = threadIdx.x;
    const int lane = tid & 63;
    const int wid  = tid >> 6;
    const int h    = tid >> 7;      // column half
    const int r    = tid & 127;     // owned row
    const int base = m * N;

    // ---- per-atom precompute ----
    if (tid < N) {
        const int i = tid;
        const int Z = atomic_numbers[base + i];
        const float rad = 0.3f + 0.02f * (float)Z;
        sg[i] = rad * rad;
        const float* na = node_attrs + (size_t)(base + i) * NELEM;
        float best = na[0]; int bi = 0;
        #pragma unroll
        for (int e = 1; e < NELEM; ++e) {
            float v = na[e];
            if (v > best) { best = v; bi = e; }     // first-max = jnp.argmax
        }
        dgv[i] = hardness[bi] + 0.5641895835477563f / rad;  // h + 1/(sqrt(pi) r)
        const float* p = positions + (size_t)(base + i) * 3;
        px[i] = p[0]; py[i] = p[1]; pz[i] = p[2];
        rhsY[i] = -eneg[base + i];   // A y = b
        rhsZ[i] = 1.0f;              // A z = 1
    }
    __syncthreads();

    // ---- fill register half-row ----
    f4 Ar[16];
    {
        const float xr = px[r], yr = py[r], zr = pz[r];
        const float sr = sg[r], dr = dgv[r];
        #pragma unroll
        for (int c = 0; c < 16; ++c) {
            f4 v;
            #pragma unroll
            for (int e = 0; e < 4; ++e) {
                const int j = 64 * h + 4 * c + e;
                float val;
                if (j == r) {
                    val = dr;
                } else {
                    const float dx = xr - px[j];
                    const float dy = yr - py[j];
                    const float dz = zr - pz[j];
                    const float d  = sqrtf(dx * dx + dy * dy + dz * dz);
                    const float g  = sqrtf(sr + sg[j]);
                    val = erff(d / (1.4142135623730951f * g)) / d;
                }
                ((float*)&v)[e] = val;
            }
            Ar[c] = v;
        }
    }

    // ================= blocked unpivoted LU, A register-resident =================
    for (int p = 0; p < NPAN; ++p) {
        const int k0 = PW * p;
        const int hp = p >> 3;
        const int q  = p & 7;
        const int gclo = 2 * p + 2;      // first trailing chunk (global index)

        // ---- stage: panel columns -> P, panel rows (trailing cols) -> Up, rhs -> Up[:,128/129]
        if (h == hp) {
            f4 a0, a1; get2(Ar, q, a0, a1);
            *(f4*)&P[r * PSTR + 0] = a0;
            *(f4*)&P[r * PSTR + 4] = a1;
        }
        if (r >= k0 && r < k0 + PW) {
            const int u = r - k0;
            #pragma unroll
            for (int c = 0; c < 16; ++c) {
                const int gc = 16 * h + c;
                if (gc >= gclo) *(f4*)&Up[u * USTR + 4 * gc] = Ar[c];
            }
        }
        if (tid < PW) {
            Up[tid * USTR + 128] = rhsY[k0 + tid];
            Up[tid * USTR + 129] = rhsZ[k0 + tid];
        }
        __syncthreads();

        // ---- panel factor: wave 0, rows k0..127 in registers, shuffle broadcasts ----
        if (wid == 0) {
            const int i0 = k0 + lane, i1 = i0 + 64;
            const bool v0 = i0 < N, v1 = i1 < N;
            float rg0[PW], rg1[PW];
            if (v0) {
                f4 a = *(const f4*)&P[i0 * PSTR], b = *(const f4*)&P[i0 * PSTR + 4];
                rg0[0]=a.x; rg0[1]=a.y; rg0[2]=a.z; rg0[3]=a.w;
                rg0[4]=b.x; rg0[5]=b.y; rg0[6]=b.z; rg0[7]=b.w;
            } else {
                #pragma unroll
                for (int j = 0; j < PW; ++j) rg0[j] = 0.0f;
            }
            if (v1) {
                f4 a = *(const f4*)&P[i1 * PSTR], b = *(const f4*)&P[i1 * PSTR + 4];
                rg1[0]=a.x; rg1[1]=a.y; rg1[2]=a.z; rg1[3]=a.w;
                rg1[4]=b.x; rg1[5]=b.y; rg1[6]=b.z; rg1[7]=b.w;
            } else {
                #pragma unroll
                for (int j = 0; j < PW; ++j) rg1[j] = 0.0f;
            }
            #pragma unroll
            for (int kk = 0; kk < PW; ++kk) {
                float pr[PW];
                #pragma unroll
                for (int j = kk; j < PW; ++j) pr[j] = __shfl(rg0[j], kk);
                const float dinv = 1.0f / pr[kk];
                if (v0 && i0 > k0 + kk) {
                    const float mult = rg0[kk] * dinv; rg0[kk] = mult;
                    #pragma unroll
                    for (int j = kk + 1; j < PW; ++j) rg0[j] -= mult * pr[j];
                }
                if (v1) {                         // i1 >= k0+64 > k0+kk always
                    const float mult = rg1[kk] * dinv; rg1[kk] = mult;
                    #pragma unroll
                    for (int j = kk + 1; j < PW; ++j) rg1[j] -= mult * pr[j];
                }
            }
            if (v0) {
                f4 a = { rg0[0], rg0[1], rg0[2], rg0[3] };
                f4 b = { rg0[4], rg0[5], rg0[6], rg0[7] };
                *(f4*)&P[i0 * PSTR] = a; *(f4*)&P[i0 * PSTR + 4] = b;
                if (lane < PW) { *(f4*)&Ublk[p][lane][0] = a; *(f4*)&Ublk[p][lane][4] = b; }
            }
            if (v1) {
                f4 a = { rg1[0], rg1[1], rg1[2], rg1[3] };
                f4 b = { rg1[4], rg1[5], rg1[6], rg1[7] };
                *(f4*)&P[i1 * PSTR] = a; *(f4*)&P[i1 * PSTR + 4] = b;
            }
        }
        __syncthreads();

        // ---- TRSM: L11^-1 * A12 over cols k0+8..127 plus rhs cols 128,129 ----
        const int ncols = 122 - k0;              // (120-k0) matrix + 2 rhs
        if (tid < ncols) {
            const int j = k0 + PW + tid;         // contiguous: matrix cols then 128,129
            float u[PW];
            #pragma unroll
            for (int kk = 0; kk < PW; ++kk) u[kk] = Up[kk * USTR + j];
            #pragma unroll
            for (int kk = 1; kk < PW; ++kk) {
                float acc = u[kk];
                #pragma unroll
                for (int t = 0; t < kk; ++t) acc -= Ublk[p][kk][t] * u[t];  // broadcast
                u[kk] = acc;
            }
            #pragma unroll
            for (int kk = 0; kk < PW; ++kk) Up[kk * USTR + j] = u[kk];
        }
        __syncthreads();

        // ---- GEMM: trailing rows update registers; owners reload; rhs persisted ----
        if (r >= k0 && r < k0 + PW) {            // owners: pull TRSM'd U back to regs
            const int u = r - k0;
            #pragma unroll
            for (int c = 0; c < 16; ++c) {
                const int gc = 16 * h + c;
                if (gc >= gclo) Ar[c] = *(const f4*)&Up[u * USTR + 4 * gc];
            }
            if (h == 1) {                        // persist forward-solved rhs rows
                rhsY[r] = Up[u * USTR + 128];
                rhsZ[r] = Up[u * USTR + 129];
            }
        }
        if (r >= k0 + PW) {
            float lA[PW];
            {
                f4 a = *(const f4*)&P[r * PSTR], b = *(const f4*)&P[r * PSTR + 4];
                lA[0]=a.x; lA[1]=a.y; lA[2]=a.z; lA[3]=a.w;
                lA[4]=b.x; lA[5]=b.y; lA[6]=b.z; lA[7]=b.w;
            }
            #pragma unroll
            for (int c = 0; c < 16; ++c) {
                const int gc = 16 * h + c;
                if (gc >= gclo) {
                    f4 acc = Ar[c];
                    #pragma unroll
                    for (int u = 0; u < PW; ++u) {
                        f4 uv = *(const f4*)&Up[u * USTR + 4 * gc];  // wave-uniform broadcast
                        acc -= uv * lA[u];
                    }
                    Ar[c] = acc;
                }
            }
            if (h == 0) {                        // rhs columns update (reads TRSM'd Up)
                float accY = rhsY[r], accZ = rhsZ[r];
                #pragma unroll
                for (int u = 0; u < PW; ++u) {
                    accY -= lA[u] * Up[u * USTR + 128];
                    accZ -= lA[u] * Up[u * USTR + 129];
                }
                rhsY[r] = accY; rhsZ[r] = accZ;
            }
        }
        __syncthreads();
    }

    // ================= blocked back substitution (both RHS) =================
    for (int pb = NPAN - 1; pb >= 0; --pb) {
        const int k0 = PW * pb;
        if (tid < 2) {                           // 8x8 upper-tri solve, Y and Z
            float* rhs = tid ? rhsZ : rhsY;
            float* sx  = tid ? sxZ  : sxY;
            float x[PW];
            #pragma unroll
            for (int kk = PW - 1; kk >= 0; --kk) {
                float acc = rhs[k0 + kk];
                #pragma unroll
                for (int jj = kk + 1; jj < PW; ++jj) acc -= Ublk[pb][kk][jj] * x[jj];
                x[kk] = acc / Ublk[pb][kk][kk];
                sx[k0 + kk] = x[kk];
            }
        }
        __syncthreads();
        const int hp = pb >> 3, q = pb & 7;
        if (h == hp && r < k0) {                 // rank-8 back-update from registers
            f4 u0, u1; get2(Ar, q, u0, u1);
            float accY = rhsY[r], accZ = rhsZ[r];
            accY -= u0.x * sxY[k0]     + u0.y * sxY[k0 + 1]
                  + u0.z * sxY[k0 + 2] + u0.w * sxY[k0 + 3]
                  + u1.x * sxY[k0 + 4] + u1.y * sxY[k0 + 5]
                  + u1.z * sxY[k0 + 6] + u1.w * sxY[k0 + 7];
            accZ -= u0.x * sxZ[k0]     + u0.y * sxZ[k0 + 1]
                  + u0.z * sxZ[k0 + 2] + u0.w * sxZ[k0 + 3]
                  + u1.x * sxZ[k0 + 4] + u1.y * sxZ[k0 + 5]
                  + u1.z * sxZ[k0 + 6] + u1.w * sxZ[k0 + 7];
            rhsY[r] = accY; rhsZ[r] = accZ;
        }
        __syncthreads();
    }

    // ---- Schur closure: lambda = (1'y - Q)/(1'z - 1); q = y - lambda z ----
    if (wid == 0) {
        float vY = sxY[lane] + sxY[lane + 64];
        float vZ = sxZ[lane] + sxZ[lane + 64];
        #pragma unroll
        for (int off = 32; off; off >>= 1) {
            vY += __shfl_xor(vY, off);
            vZ += __shfl_xor(vZ, off);
        }
        if (lane == 0) lamS = (vY - total_charge[m]) / (vZ - 1.0f);
    }
    __syncthreads();
    if (tid < N) out[base + tid] = sxY[tid] - lamS * sxZ[tid];
}

extern "C" void kernel_launch(void* const* d_in, const int* in_sizes, int n_in,
                              void* d_out, int out_size, void* d_ws, size_t ws_size,
                              hipStream_t stream) {
    const float* eneg           = (const float*)d_in[0];
    const float* positions      = (const float*)d_in[1];
    const float* node_attrs     = (const float*)d_in[2];
    const float* hardness       = (const float*)d_in[3];
    const float* total_charge   = (const float*)d_in[4];
    // d_in[5] = batch (unused: equal-sized sorted molecules)
    const int*   atomic_numbers = (const int*)d_in[6];
    float* out = (float*)d_out;

    ceq_solve_kernel<<<NMOL, BLOCK, 0, stream>>>(
        eneg, positions, node_attrs, hardness, total_charge, atomic_numbers, out);
}

// Round 6
// 247.578 us; speedup vs baseline: 1.1123x; 1.1123x over previous
//
#include <hip/hip_runtime.h>
#include <math.h>

#define NMOL  1024
#define N     128          // atoms per molecule (Schur-reduced SPD system size)
#define NELEM 10
#define BLOCK 256
#define PW    8            // panel width
#define NPAN  16           // 128 / 8
#define PSTR  12           // panel-column buffer row stride (floats)
#define USTR  132          // U-panel row stride (cols 0..129: 128=rhsY, 129=rhsZ)

typedef __attribute__((ext_vector_type(4))) float f4;

// wave w (=tid>>6) owns column chunks [8w, 8w+8) (32 cols).
// lane l owns rows r0=2l, r1=2l+1 of those columns: Ar0[8], Ar1[8] (f4 each).

__global__ __launch_bounds__(BLOCK, 4) void ceq_solve_kernel(
    const float* __restrict__ eneg,
    const float* __restrict__ positions,
    const float* __restrict__ node_attrs,
    const float* __restrict__ hardness,
    const float* __restrict__ total_charge,
    const int*   __restrict__ atomic_numbers,
    float* __restrict__ out)
{
    __shared__ __align__(16) float P[N * PSTR];        // staged panel columns (128 x 8)
    __shared__ __align__(16) float Up[PW * USTR];      // staged panel rows (8 x 130)
    __shared__ __align__(16) float Ublk[NPAN][PW][PW]; // per-panel 8x8 diag blocks
    __shared__ float rhsY[N], rhsZ[N];
    __shared__ float sxY[N], sxZ[N];
    __shared__ float px[N], py[N], pz[N], sg[N], dgv[N];
    __shared__ float lamS;

    const int m    = blockIdx.x;
    const int tid  = threadIdx.x;
    const int lane = tid & 63;
    const int wid  = tid >> 6;
    const int r0   = 2 * lane;
    const int r1   = r0 + 1;
    const int col0 = 32 * wid;
    const int base = m * N;

    // ---- per-atom precompute ----
    if (tid < N) {
        const int i = tid;
        const int Z = atomic_numbers[base + i];
        const float rad = 0.3f + 0.02f * (float)Z;
        sg[i] = rad * rad;
        const float* na = node_attrs + (size_t)(base + i) * NELEM;
        float best = na[0]; int bi = 0;
        #pragma unroll
        for (int e = 1; e < NELEM; ++e) {
            float v = na[e];
            if (v > best) { best = v; bi = e; }     // first-max = jnp.argmax
        }
        dgv[i] = hardness[bi] + 0.5641895835477563f / rad;  // h + 1/(sqrt(pi) r)
        const float* p = positions + (size_t)(base + i) * 3;
        px[i] = p[0]; py[i] = p[1]; pz[i] = p[2];
        rhsY[i] = -eneg[base + i];   // A y = b
        rhsZ[i] = 1.0f;              // A z = 1
    }
    __syncthreads();

    // ---- fill register tiles: rows r0,r1 x cols [col0, col0+32) ----
    f4 Ar0[8], Ar1[8];
    {
        const float x0 = px[r0], y0 = py[r0], z0 = pz[r0], s0 = sg[r0], d0 = dgv[r0];
        const float x1 = px[r1], y1 = py[r1], z1 = pz[r1], s1 = sg[r1], d1 = dgv[r1];
        #pragma unroll
        for (int c = 0; c < 8; ++c) {
            f4 v0, v1;
            #pragma unroll
            for (int e = 0; e < 4; ++e) {
                const int j = col0 + 4 * c + e;
                const float xj = px[j], yj = py[j], zj = pz[j], sj = sg[j];
                float a0, a1;
                if (j == r0) a0 = d0;
                else {
                    const float dx = x0 - xj, dy = y0 - yj, dz = z0 - zj;
                    const float d = sqrtf(dx * dx + dy * dy + dz * dz);
                    a0 = erff(d / (1.4142135623730951f * sqrtf(s0 + sj))) / d;
                }
                if (j == r1) a1 = d1;
                else {
                    const float dx = x1 - xj, dy = y1 - yj, dz = z1 - zj;
                    const float d = sqrtf(dx * dx + dy * dy + dz * dz);
                    a1 = erff(d / (1.4142135623730951f * sqrtf(s1 + sj))) / d;
                }
                ((float*)&v0)[e] = a0;
                ((float*)&v1)[e] = a1;
            }
            Ar0[c] = v0; Ar1[c] = v1;
        }
    }

    // ================= blocked unpivoted LU, A register-resident =================
    for (int p = 0; p < NPAN; ++p) {
        const int k0   = PW * p;
        const int gclo = 2 * p + 2;          // first trailing chunk (global)
        const int wp   = p >> 2;             // wave holding panel columns

        // ---- stage panel columns (rows >= k0) -> P ----
        if (wid == wp && lane >= 4 * p) {
            f4 a00, a01, a10, a11;
            switch (p & 3) {
                case 0:  a00 = Ar0[0]; a01 = Ar0[1]; a10 = Ar1[0]; a11 = Ar1[1]; break;
                case 1:  a00 = Ar0[2]; a01 = Ar0[3]; a10 = Ar1[2]; a11 = Ar1[3]; break;
                case 2:  a00 = Ar0[4]; a01 = Ar0[5]; a10 = Ar1[4]; a11 = Ar1[5]; break;
                default: a00 = Ar0[6]; a01 = Ar0[7]; a10 = Ar1[6]; a11 = Ar1[7]; break;
            }
            *(f4*)&P[r0 * PSTR + 0] = a00; *(f4*)&P[r0 * PSTR + 4] = a01;
            *(f4*)&P[r1 * PSTR + 0] = a10; *(f4*)&P[r1 * PSTR + 4] = a11;
        }
        // ---- stage panel rows (trailing chunks of quarter) -> Up ----
        if (lane >= 4 * p && lane < 4 * p + 4) {
            const int u0 = r0 - k0, u1 = u0 + 1;
            #pragma unroll
            for (int c = 0; c < 8; ++c) {
                const int gc = 8 * wid + c;
                if (gc >= gclo) {
                    *(f4*)&Up[u0 * USTR + 4 * gc] = Ar0[c];
                    *(f4*)&Up[u1 * USTR + 4 * gc] = Ar1[c];
                }
            }
        }
        if (tid < PW) {
            Up[tid * USTR + 128] = rhsY[k0 + tid];
            Up[tid * USTR + 129] = rhsZ[k0 + tid];
        }
        __syncthreads();

        // ---- panel factor: wave 0, rows k0..127, shuffle broadcasts ----
        if (wid == 0) {
            const int i0 = k0 + lane, i1 = i0 + 64;
            const bool v0 = i0 < N, v1 = i1 < N;
            float rg0[PW], rg1[PW];
            if (v0) {
                f4 a = *(const f4*)&P[i0 * PSTR], b = *(const f4*)&P[i0 * PSTR + 4];
                rg0[0]=a.x; rg0[1]=a.y; rg0[2]=a.z; rg0[3]=a.w;
                rg0[4]=b.x; rg0[5]=b.y; rg0[6]=b.z; rg0[7]=b.w;
            } else {
                #pragma unroll
                for (int j = 0; j < PW; ++j) rg0[j] = 0.0f;
            }
            if (v1) {
                f4 a = *(const f4*)&P[i1 * PSTR], b = *(const f4*)&P[i1 * PSTR + 4];
                rg1[0]=a.x; rg1[1]=a.y; rg1[2]=a.z; rg1[3]=a.w;
                rg1[4]=b.x; rg1[5]=b.y; rg1[6]=b.z; rg1[7]=b.w;
            } else {
                #pragma unroll
                for (int j = 0; j < PW; ++j) rg1[j] = 0.0f;
            }
            #pragma unroll
            for (int kk = 0; kk < PW; ++kk) {
                float pr[PW];
                #pragma unroll
                for (int j = kk; j < PW; ++j) pr[j] = __shfl(rg0[j], kk);
                const float dinv = 1.0f / pr[kk];
                if (v0 && i0 > k0 + kk) {
                    const float mult = rg0[kk] * dinv; rg0[kk] = mult;
                    #pragma unroll
                    for (int j = kk + 1; j < PW; ++j) rg0[j] -= mult * pr[j];
                }
                if (v1) {
                    const float mult = rg1[kk] * dinv; rg1[kk] = mult;
                    #pragma unroll
                    for (int j = kk + 1; j < PW; ++j) rg1[j] -= mult * pr[j];
                }
            }
            if (v0) {
                f4 a = { rg0[0], rg0[1], rg0[2], rg0[3] };
                f4 b = { rg0[4], rg0[5], rg0[6], rg0[7] };
                *(f4*)&P[i0 * PSTR] = a; *(f4*)&P[i0 * PSTR + 4] = b;
                if (lane < PW) { *(f4*)&Ublk[p][lane][0] = a; *(f4*)&Ublk[p][lane][4] = b; }
            }
            if (v1) {
                f4 a = { rg1[0], rg1[1], rg1[2], rg1[3] };
                f4 b = { rg1[4], rg1[5], rg1[6], rg1[7] };
                *(f4*)&P[i1 * PSTR] = a; *(f4*)&P[i1 * PSTR + 4] = b;
            }
        }
        __syncthreads();

        // ---- TRSM: L11^-1 over cols k0+8..127 plus rhs cols 128,129 ----
        const int ncols = 122 - k0;
        if (tid < ncols) {
            const int j = k0 + PW + tid;
            float u[PW];
            #pragma unroll
            for (int kk = 0; kk < PW; ++kk) u[kk] = Up[kk * USTR + j];
            #pragma unroll
            for (int kk = 1; kk < PW; ++kk) {
                float acc = u[kk];
                #pragma unroll
                for (int t = 0; t < kk; ++t) acc -= Ublk[p][kk][t] * u[t];
                u[kk] = acc;
            }
            #pragma unroll
            for (int kk = 0; kk < PW; ++kk) Up[kk * USTR + j] = u[kk];
        }
        __syncthreads();

        // ---- owner reload, rhs persist, GEMM ----
        if (lane >= 4 * p && lane < 4 * p + 4) {     // owners pull TRSM'd U to regs
            const int u0 = r0 - k0, u1 = u0 + 1;
            #pragma unroll
            for (int c = 0; c < 8; ++c) {
                const int gc = 8 * wid + c;
                if (gc >= gclo) {
                    Ar0[c] = *(const f4*)&Up[u0 * USTR + 4 * gc];
                    Ar1[c] = *(const f4*)&Up[u1 * USTR + 4 * gc];
                }
            }
        }
        if (tid < PW) {                               // persist forward-solved rhs rows
            rhsY[k0 + tid] = Up[tid * USTR + 128];
            rhsZ[k0 + tid] = Up[tid * USTR + 129];
        }
        const bool hasmat = (8 * wid + 7) >= gclo;
        if (lane >= 4 * p + 4) {                      // rows >= k0+8
            float lA0[PW], lA1[PW];
            if (hasmat || wid == 0) {
                f4 a = *(const f4*)&P[r0 * PSTR], b = *(const f4*)&P[r0 * PSTR + 4];
                lA0[0]=a.x; lA0[1]=a.y; lA0[2]=a.z; lA0[3]=a.w;
                lA0[4]=b.x; lA0[5]=b.y; lA0[6]=b.z; lA0[7]=b.w;
                f4 c2 = *(const f4*)&P[r1 * PSTR], d2 = *(const f4*)&P[r1 * PSTR + 4];
                lA1[0]=c2.x; lA1[1]=c2.y; lA1[2]=c2.z; lA1[3]=c2.w;
                lA1[4]=d2.x; lA1[5]=d2.y; lA1[6]=d2.z; lA1[7]=d2.w;
            }
            if (hasmat) {
                #pragma unroll
                for (int c = 0; c < 8; ++c) {
                    const int gc = 8 * wid + c;
                    if (gc >= gclo) {
                        f4 acc0 = Ar0[c], acc1 = Ar1[c];
                        #pragma unroll
                        for (int u = 0; u < PW; ++u) {
                            const f4 uv = *(const f4*)&Up[u * USTR + 4 * gc]; // 1 wave only
                            acc0 -= uv * lA0[u];
                            acc1 -= uv * lA1[u];
                        }
                        Ar0[c] = acc0; Ar1[c] = acc1;
                    }
                }
            }
            if (wid == 0) {                           // rhs columns update
                float yy0 = rhsY[r0], yy1 = rhsY[r1];
                float zz0 = rhsZ[r0], zz1 = rhsZ[r1];
                #pragma unroll
                for (int u = 0; u < PW; ++u) {
                    const float uy = Up[u * USTR + 128];
                    const float uz = Up[u * USTR + 129];
                    yy0 -= lA0[u] * uy; yy1 -= lA1[u] * uy;
                    zz0 -= lA0[u] * uz; zz1 -= lA1[u] * uz;
                }
                rhsY[r0] = yy0; rhsY[r1] = yy1;
                rhsZ[r0] = zz0; rhsZ[r1] = zz1;
            }
        }
        __syncthreads();
    }

    // ================= blocked back substitution (both RHS) =================
    for (int pb = NPAN - 1; pb >= 0; --pb) {
        const int k0 = PW * pb;
        if (tid < 2) {                                // 8x8 upper-tri solve, Y and Z
            float* rhs = tid ? rhsZ : rhsY;
            float* sx  = tid ? sxZ  : sxY;
            float x[PW];
            #pragma unroll
            for (int kk = PW - 1; kk >= 0; --kk) {
                float acc = rhs[k0 + kk];
                #pragma unroll
                for (int jj = kk + 1; jj < PW; ++jj) acc -= Ublk[pb][kk][jj] * x[jj];
                x[kk] = acc / Ublk[pb][kk][kk];
                sx[k0 + kk] = x[kk];
            }
        }
        __syncthreads();
        if (wid == (pb >> 2) && lane < 4 * pb) {      // rank-8 back-update from regs
            f4 a00, a01, a10, a11;
            switch (pb & 3) {
                case 0:  a00 = Ar0[0]; a01 = Ar0[1]; a10 = Ar1[0]; a11 = Ar1[1]; break;
                case 1:  a00 = Ar0[2]; a01 = Ar0[3]; a10 = Ar1[2]; a11 = Ar1[3]; break;
                case 2:  a00 = Ar0[4]; a01 = Ar0[5]; a10 = Ar1[4]; a11 = Ar1[5]; break;
                default: a00 = Ar0[6]; a01 = Ar0[7]; a10 = Ar1[6]; a11 = Ar1[7]; break;
            }
            float yy0 = rhsY[r0], yy1 = rhsY[r1];
            float zz0 = rhsZ[r0], zz1 = rhsZ[r1];
            yy0 -= a00.x*sxY[k0]   + a00.y*sxY[k0+1] + a00.z*sxY[k0+2] + a00.w*sxY[k0+3]
                 + a01.x*sxY[k0+4] + a01.y*sxY[k0+5] + a01.z*sxY[k0+6] + a01.w*sxY[k0+7];
            yy1 -= a10.x*sxY[k0]   + a10.y*sxY[k0+1] + a10.z*sxY[k0+2] + a10.w*sxY[k0+3]
                 + a11.x*sxY[k0+4] + a11.y*sxY[k0+5] + a11.z*sxY[k0+6] + a11.w*sxY[k0+7];
            zz0 -= a00.x*sxZ[k0]   + a00.y*sxZ[k0+1] + a00.z*sxZ[k0+2] + a00.w*sxZ[k0+3]
                 + a01.x*sxZ[k0+4] + a01.y*sxZ[k0+5] + a01.z*sxZ[k0+6] + a01.w*sxZ[k0+7];
            zz1 -= a10.x*sxZ[k0]   + a10.y*sxZ[k0+1] + a10.z*sxZ[k0+2] + a10.w*sxZ[k0+3]
                 + a11.x*sxZ[k0+4] + a11.y*sxZ[k0+5] + a11.z*sxZ[k0+6] + a11.w*sxZ[k0+7];
            rhsY[r0] = yy0; rhsY[r1] = yy1;
            rhsZ[r0] = zz0; rhsZ[r1] = zz1;
        }
        __syncthreads();
    }

    // ---- Schur closure: lambda = (1'y - Q)/(1'z - 1); q = y - lambda z ----
    if (wid == 0) {
        float vY = sxY[lane] + sxY[lane + 64];
        float vZ = sxZ[lane] + sxZ[lane + 64];
        #pragma unroll
        for (int off = 32; off; off >>= 1) {
            vY += __shfl_xor(vY, off);
            vZ += __shfl_xor(vZ, off);
        }
        if (lane == 0) lamS = (vY - total_charge[m]) / (vZ - 1.0f);
    }
    __syncthreads();
    if (tid < N) out[base + tid] = sxY[tid] - lamS * sxZ[tid];
}

extern "C" void kernel_launch(void* const* d_in, const int* in_sizes, int n_in,
                              void* d_out, int out_size, void* d_ws, size_t ws_size,
                              hipStream_t stream) {
    const float* eneg           = (const float*)d_in[0];
    const float* positions      = (const float*)d_in[1];
    const float* node_attrs     = (const float*)d_in[2];
    const float* hardness       = (const float*)d_in[3];
    const float* total_charge   = (const float*)d_in[4];
    // d_in[5] = batch (unused: equal-sized sorted molecules)
    const int*   atomic_numbers = (const int*)d_in[6];
    float* out = (float*)d_out;

    ceq_solve_kernel<<<NMOL, BLOCK, 0, stream>>>(
        eneg, positions, node_attrs, hardness, total_charge, atomic_numbers, out);
}